// Round 2
// baseline (9785.613 us; speedup 1.0000x reference)
//
#include <hip/hip_runtime.h>

#define T_ 100
#define B_ 256
#define N_ 512
#define BN (B_ * N_)
#define TBN ((size_t)T_ * BN)

typedef short s16x8 __attribute__((ext_vector_type(8)));
typedef float f32x4 __attribute__((ext_vector_type(4)));
typedef unsigned short u16;

__device__ __forceinline__ float bf2f(u16 u) {
  union { unsigned int i; float f; } v; v.i = ((unsigned int)u) << 16; return v.f;
}
__device__ __forceinline__ u16 f2bf(float f) {
  union { float f; unsigned int i; } v; v.f = f;
  unsigned int x = v.i;
  return (u16)((x + 0x7fffu + ((x >> 16) & 1u)) >> 16);
}

struct P {
  // fp32 inputs
  const float *v, *p0, *encW, *encb, *Win, *bin, *tauMin, *tauAin;
  const float *Wd, *bd, *Wr, *br, *tauMr, *tauAr, *Wout, *bout, *tauMo;
  // workspace
  u16 *wdS[3], *wrS[3], *woS[3];  // 3-way bf16 weight splits (hi/mid/lo)
  u16 *spin[2];                   // input-layer spikes (bf16 {0,1}), parity buffered
  u16 *spr[3][2];                 // recurrent spikes, parity buffered
  float *memin[2], *adin[2];      // input-layer state (redundant writers -> parity)
  float *memr, *adr;              // [3][B*N]
  float *memout;                  // [B*N]
  float *cst;  // [0,512) a_in | [512,1024) ro_in | [1024,2560) a_rnn |
               // [2560,4096) ro_rnn | [4096,4608) a_out
  float *out;
  int t;
};

// ALIF epilogue, recurrent layer l. C/D layout: col=lane&15, row=quad*4+reg.
__device__ __forceinline__ void alif_epi(const P& p, int l, f32x4 acc, int r_base,
                                         int quad, int n, int t, int pw, int pr) {
  const float alpha = p.cst[1024 + l * 512 + n];
  const float ro    = p.cst[2560 + l * 512 + n];
  const float bias  = p.bd[l * 512 + n] + p.br[l * 512 + n];
  const u16* spv = p.spr[l][pr];
  u16* spc = p.spr[l][pw];
  float* memr = p.memr + l * BN;
  float* adr  = p.adr + l * BN;
  float* outm = p.out + (size_t)(3 + 2 * l) * TBN + (size_t)t * BN;
  float* outs = p.out + (size_t)(4 + 2 * l) * TBN + (size_t)t * BN;
#pragma unroll
  for (int i = 0; i < 4; ++i) {
    const int b = r_base + quad * 4 + i;
    const int idx = b * 512 + n;
    const float spk = bf2f(spv[idx]);
    float ad = adr[idx];
    float m  = memr[idx];
    ad = ro * ad + (1.f - ro) * spk;
    const float Bth = 0.01f + 1.8f * ad;
    m = m * alpha + (1.f - alpha) * (acc[i] + bias) - Bth * spk;
    const float ns = (m - Bth) > 0.f ? 1.f : 0.f;
    memr[idx] = m;
    adr[idx]  = ad;
    spc[idx]  = (ns != 0.f) ? (u16)0x3F80 : (u16)0;
    outm[idx] = m;
    outs[idx] = ns;
  }
}

// Triple-split dual-matrix GEMM accumulate: acc_s += A(spikes) @ W_s^T for s in {hi,mid,lo}.
__device__ __forceinline__ void gemm3(const u16* A, int arow, const u16* Wh,
                                      const u16* Wm, const u16* Wl, int n, int quad,
                                      f32x4& a0, f32x4& a1, f32x4& a2) {
#pragma unroll 4
  for (int kb = 0; kb < 16; ++kb) {
    const int kk = kb * 32 + quad * 8;
    s16x8 af = *(const s16x8*)(A + arow * 512 + kk);
    a0 = __builtin_amdgcn_mfma_f32_16x16x32_bf16(af, *(const s16x8*)(Wh + n * 512 + kk), a0, 0, 0, 0);
    a1 = __builtin_amdgcn_mfma_f32_16x16x32_bf16(af, *(const s16x8*)(Wm + n * 512 + kk), a1, 0, 0, 0);
    a2 = __builtin_amdgcn_mfma_f32_16x16x32_bf16(af, *(const s16x8*)(Wl + n * 512 + kk), a2, 0, 0, 0);
  }
}

// Readout(t-1) + input-layer ALIF(t) + layer-0 GEMM/ALIF(t).
__global__ __launch_bounds__(128) void k_step_l1r(P p) {
  const int wg = blockIdx.x, rb = wg >> 5, cc = wg & 31;
  const int tid = threadIdx.x;
  const int wave = tid >> 6, lane = tid & 63;
  const int lrow = lane & 15, quad = lane >> 4;
  const int t = p.t, pw = t & 1, pr = pw ^ 1;
  __shared__ u16 spin_s[32 * 512];

  const int n = cc * 16 + lrow;
  const int r_base = rb * 32 + wave * 16;

  if (t > 0) {  // ---- readout for step t-1 ----
    f32x4 a0 = {0.f,0.f,0.f,0.f}, a1 = a0, a2 = a0;
    gemm3(p.spr[2][pr], r_base + lrow, p.woS[0], p.woS[1], p.woS[2], n, quad, a0, a1, a2);
    const float ao = p.cst[4096 + n];
    const float bo = p.bout[n];
#pragma unroll
    for (int i = 0; i < 4; ++i) {
      const int b = r_base + quad * 4 + i;
      const int idx = b * 512 + n;
      const float dot = (a0[i] + a1[i]) + a2[i];
      float m = p.memout[idx];
      m = m * ao + (1.f - ao) * (dot + bo);
      p.memout[idx] = m;
      const float g = m > 0.f ? m : 0.f;
      p.out[(size_t)0 * TBN + (size_t)(t - 1) * BN + idx] = g;
      p.out[(size_t)9 * TBN + (size_t)(t - 1) * BN + idx] = g;
    }
  }

  if (t < T_) {
    // ---- input-layer ALIF (redundant across cc; identical values, parity buffers) ----
    for (int e = tid; e < 32 * 512; e += 128) {
      const int rl = e >> 9, nn = e & 511;
      const int b = rb * 32 + rl;
      const int idx = b * 512 + nn;
      const float inp = p.v[(t * 256 + b) * 2 + 0] * p.Win[nn * 2 + 0]
                      + p.v[(t * 256 + b) * 2 + 1] * p.Win[nn * 2 + 1] + p.bin[nn];
      const float alpha = p.cst[nn], ro = p.cst[512 + nn];
      const float spk = bf2f(p.spin[pr][idx]);
      float ad = p.adin[pr][idx];
      float m  = p.memin[pr][idx];
      ad = ro * ad + (1.f - ro) * spk;
      const float Bth = 0.01f + 1.8f * ad;
      m = m * alpha + (1.f - alpha) * inp - Bth * spk;
      const float ns = (m - Bth) > 0.f ? 1.f : 0.f;
      p.memin[pw][idx] = m;
      p.adin[pw][idx]  = ad;
      const u16 sb = (ns != 0.f) ? (u16)0x3F80 : (u16)0;
      p.spin[pw][idx] = sb;
      spin_s[(rl << 9) + nn] = sb;
      if (cc == 0) {
        p.out[(size_t)1 * TBN + (size_t)t * BN + idx] = m;
        p.out[(size_t)2 * TBN + (size_t)t * BN + idx] = ns;
      }
    }
    __syncthreads();

    // ---- layer 0: inp = x@Wd0^T + sp_r0@Wr0^T, then ALIF ----
    f32x4 a0 = {0.f,0.f,0.f,0.f}, a1 = a0, a2 = a0;
    gemm3(spin_s, wave * 16 + lrow, p.wdS[0], p.wdS[1], p.wdS[2], n, quad, a0, a1, a2);
    gemm3(p.spr[0][pr], r_base + lrow, p.wrS[0], p.wrS[1], p.wrS[2], n, quad, a0, a1, a2);
    f32x4 acc;
#pragma unroll
    for (int i = 0; i < 4; ++i) acc[i] = (a0[i] + a1[i]) + a2[i];
    alif_epi(p, 0, acc, r_base, quad, n, t, pw, pr);
  }
}

// Recurrent layer l in {1,2}.
__global__ __launch_bounds__(128) void k_step_mid(P p, int l) {
  const int wg = blockIdx.x, rb = wg >> 5, cc = wg & 31;
  const int wave = threadIdx.x >> 6, lane = threadIdx.x & 63;
  const int lrow = lane & 15, quad = lane >> 4;
  const int t = p.t, pw = t & 1, pr = pw ^ 1;
  const int n = cc * 16 + lrow;
  const int r_base = rb * 32 + wave * 16;
  const int arow = r_base + lrow;
  const size_t wo = (size_t)l * 512 * 512;

  f32x4 a0 = {0.f,0.f,0.f,0.f}, a1 = a0, a2 = a0;
  gemm3(p.spr[l - 1][pw], arow, p.wdS[0] + wo, p.wdS[1] + wo, p.wdS[2] + wo, n, quad, a0, a1, a2);
  gemm3(p.spr[l][pr],     arow, p.wrS[0] + wo, p.wrS[1] + wo, p.wrS[2] + wo, n, quad, a0, a1, a2);
  f32x4 acc;
#pragma unroll
  for (int i = 0; i < 4; ++i) acc[i] = (a0[i] + a1[i]) + a2[i];
  alif_epi(p, l, acc, r_base, quad, n, t, pw, pr);
}

// 3-way bf16 split of fp32 weights (residual <= 2^-27 |w|).
__global__ void k_split(P p) {
  const int stride = gridDim.x * blockDim.x;
  const int i0 = blockIdx.x * blockDim.x + threadIdx.x;
  for (int i = i0; i < 3 * N_ * N_; i += stride) {
    float w = p.Wd[i];
    u16 h = f2bf(w); float r1 = w - bf2f(h);
    u16 m = f2bf(r1); float r2 = r1 - bf2f(m);
    p.wdS[0][i] = h; p.wdS[1][i] = m; p.wdS[2][i] = f2bf(r2);
    w = p.Wr[i];
    h = f2bf(w); r1 = w - bf2f(h);
    m = f2bf(r1); r2 = r1 - bf2f(m);
    p.wrS[0][i] = h; p.wrS[1][i] = m; p.wrS[2][i] = f2bf(r2);
  }
  for (int i = i0; i < N_ * N_; i += stride) {
    float w = p.Wout[i];
    u16 h = f2bf(w); float r1 = w - bf2f(h);
    u16 m = f2bf(r1); float r2 = r1 - bf2f(m);
    p.woS[0][i] = h; p.woS[1][i] = m; p.woS[2][i] = f2bf(r2);
  }
}

__global__ void k_init_misc(P p) {
  const long stride = (long)gridDim.x * blockDim.x;
  const long tid0 = (long)blockIdx.x * blockDim.x + threadIdx.x;
  for (long i = tid0; i < 512; i += stride) {
    p.cst[i]        = expf(-1.f / p.tauMin[i]);
    p.cst[512 + i]  = expf(-1.f / p.tauAin[i]);
    p.cst[4096 + i] = expf(-1.f / p.tauMo[i]);
  }
  for (long i = tid0; i < 1536; i += stride) {
    p.cst[1024 + i] = expf(-1.f / p.tauMr[i]);
    p.cst[2560 + i] = expf(-1.f / p.tauAr[i]);
  }
  for (long i = tid0; i < BN; i += stride) {
    p.spin[1][i] = 0;
    p.spr[0][1][i] = 0;
    p.spr[1][1][i] = 0;
    p.spr[2][1][i] = 0;
    p.adin[1][i] = 0.01f;
    p.adr[i] = 0.01f;
    p.adr[BN + i] = 0.01f;
    p.adr[2 * BN + i] = 0.01f;
  }
}

// Membrane init from place-code encoders (fp32 VALU).
__global__ __launch_bounds__(128) void k_init_enc(P p) {
  const int wg = blockIdx.x, rb = wg >> 5, cc = wg & 31;
  for (int a = threadIdx.x; a < 2560; a += 128) {
    const int l = a >> 9, rem = a & 511;
    const int b = rb * 32 + (rem >> 4), n = cc * 16 + (rem & 15);
    const float* ap = p.p0 + b * 512;
    const float* wp = p.encW + ((size_t)(l * 512 + n)) * 512;
    float acc = 0.f;
    for (int k = 0; k < 512; ++k) acc += (ap[k] * 1000.0f) * wp[k];
    const float x = acc + p.encb[l * 512 + n];
    const float val = 0.015f * (1.f / (1.f + expf(-x)));
    const int idx = b * 512 + n;
    if (l == 0)      p.memin[1][idx] = val;
    else if (l <= 3) p.memr[(l - 1) * BN + idx] = val;
    else             p.memout[idx] = val;
  }
}

extern "C" void kernel_launch(void* const* d_in, const int* in_sizes, int n_in,
                              void* d_out, int out_size, void* d_ws, size_t ws_size,
                              hipStream_t stream) {
  P p;
  p.v      = (const float*)d_in[0];
  p.p0     = (const float*)d_in[1];
  p.encW   = (const float*)d_in[2];
  p.encb   = (const float*)d_in[3];
  p.Win    = (const float*)d_in[4];
  p.bin    = (const float*)d_in[5];
  p.tauMin = (const float*)d_in[6];
  p.tauAin = (const float*)d_in[7];
  p.Wd     = (const float*)d_in[8];
  p.bd     = (const float*)d_in[9];
  p.Wr     = (const float*)d_in[10];
  p.br     = (const float*)d_in[11];
  p.tauMr  = (const float*)d_in[12];
  p.tauAr  = (const float*)d_in[13];
  p.Wout   = (const float*)d_in[14];
  p.bout   = (const float*)d_in[15];
  p.tauMo  = (const float*)d_in[16];
  p.out    = (float*)d_out;

  char* w = (char*)d_ws;
  size_t off = 0;
  auto carve = [&](size_t bytes) -> void* {
    void* r = (void*)(w + off);
    off += (bytes + 255) & ~(size_t)255;
    return r;
  };
  for (int s = 0; s < 3; ++s) p.wdS[s] = (u16*)carve((size_t)3 * N_ * N_ * 2);
  for (int s = 0; s < 3; ++s) p.wrS[s] = (u16*)carve((size_t)3 * N_ * N_ * 2);
  for (int s = 0; s < 3; ++s) p.woS[s] = (u16*)carve((size_t)N_ * N_ * 2);
  for (int q = 0; q < 2; ++q) p.spin[q] = (u16*)carve((size_t)BN * 2);
  for (int l = 0; l < 3; ++l)
    for (int q = 0; q < 2; ++q) p.spr[l][q] = (u16*)carve((size_t)BN * 2);
  for (int q = 0; q < 2; ++q) p.memin[q] = (float*)carve((size_t)BN * 4);
  for (int q = 0; q < 2; ++q) p.adin[q] = (float*)carve((size_t)BN * 4);
  p.memr   = (float*)carve((size_t)3 * BN * 4);
  p.adr    = (float*)carve((size_t)3 * BN * 4);
  p.memout = (float*)carve((size_t)BN * 4);
  p.cst    = (float*)carve((size_t)4608 * 4);

  p.t = 0;
  hipLaunchKernelGGL(k_split, dim3(512), dim3(256), 0, stream, p);
  hipLaunchKernelGGL(k_init_misc, dim3(256), dim3(256), 0, stream, p);
  hipLaunchKernelGGL(k_init_enc, dim3(256), dim3(128), 0, stream, p);
  for (int t = 0; t <= T_; ++t) {
    p.t = t;
    hipLaunchKernelGGL(k_step_l1r, dim3(256), dim3(128), 0, stream, p);
    if (t < T_) {
      hipLaunchKernelGGL(k_step_mid, dim3(256), dim3(128), 0, stream, p, 1);
      hipLaunchKernelGGL(k_step_mid, dim3(256), dim3(128), 0, stream, p, 2);
    }
  }
}